// Round 2
// baseline (44.573 us; speedup 1.0000x reference)
//
#include <hip/hip_runtime.h>
#include <hip/hip_cooperative_groups.h>

namespace cg = cooperative_groups;

// out[b,n,d] = (x@Wq+bq)[b,n,d] * kv[b,d],  kv[b,d] = sum_m ((x@Wk+bk)*(x@Wv+bv))[b,m,d]
// B=4, N=1024, D=128, fp32 in/out.
//
// R2: MFMA bf16x3-split (xh*wh + xl*wh + xh*wl, fp32 accum; rel err ~2^-16)
// in a SINGLE cooperative kernel:
//   grid 256 blocks x 512 thr (1 block/CU, co-resident for grid.sync).
//   block = (mg: 64 rows) x (cp: 32 cols).  8 waves = 4 row-subtiles x 2 col-subtiles,
//   each wave one 16x16 MFMA tile per matrix (q,k,v).
//   Phase 0: block converts its W slab (3 mats x 128k x 32cols) to bf16 hi/lo in LDS.
//   Phase 1: 36 MFMAs/wave (4 k-steps x 3 split-terms x 3 mats); k*v row-reduced
//            (4 regs + shfl_xor 16/32 + LDS across waves) -> 32-float partial -> ws.
//   grid.sync()
//   Phase 2: kv = sum of 16 row-group partials (fixed order); out = (q+bq)*kv from regs.
//
// MFMA 16x16x32 frag maps: A: row=lane&15, k=(lane>>4)*8+j; B: col=lane&15, same k-map
// (identical k-permutation for A and B => any permutation error cancels in the dot);
// C/D: col=lane&15, row=(lane>>4)*4+reg (HW-verified mapping).

#define BB 4
#define NN 1024
#define DD 128
#define KP 136   // LDS k-stride (bf16): 272B rows -> 16B-aligned frags, banks uniform

typedef __attribute__((ext_vector_type(8))) short short8;
typedef __attribute__((ext_vector_type(4))) float f32x4;

union AB { short8 s; unsigned int u[4]; };

static __device__ __forceinline__ unsigned int pack_bf16(float a, float b) {
    // low half = bf16(a) (truncate; residual goes to the lo-term), high half = bf16(b)
    return (__float_as_uint(a) >> 16) | (__float_as_uint(b) & 0xFFFF0000u);
}

__global__ __launch_bounds__(512, 2) void fused(
    const float* __restrict__ x,
    const float* __restrict__ Wq, const float* __restrict__ bq,
    const float* __restrict__ Wk, const float* __restrict__ bk,
    const float* __restrict__ Wv, const float* __restrict__ bv,
    float* __restrict__ out, float* __restrict__ ws)
{
    __shared__ unsigned short wt[3][2][32][KP];  // [mat][hi/lo][col][k] ~52 KB
    __shared__ float red[8][32];

    const int bid = blockIdx.x;
    const int cp  = bid & 3;            // col group: cols cp*32 .. cp*32+31
    const int mg  = bid >> 2;           // 0..63: rows mg*64 .. mg*64+63
    const int b   = mg >> 4;
    const int tid = threadIdx.x;
    const int cbase = cp * 32;

    cg::grid_group grid = cg::this_grid();

    // ---- phase 0: W slab -> bf16 hi/lo in LDS (block-local, no grid dep) ----
    {
        const float* Wsrc[3] = {Wq, Wk, Wv};
#pragma unroll
        for (int j = 0; j < 24; ++j) {
            const int e   = tid + j * 512;    // 0..12287 = 3 mats x 128k x 32c
            const int mat = e >> 12;
            const int r   = e & 4095;
            const int k   = r >> 5;
            const int c   = r & 31;           // consecutive per lane -> coalesced read
            const float w = Wsrc[mat][k * DD + cbase + c];
            const unsigned int hb = __float_as_uint(w) & 0xFFFF0000u;
            const float lo = w - __uint_as_float(hb);
            wt[mat][0][c][k] = (unsigned short)(hb >> 16);
            wt[mat][1][c][k] = (unsigned short)(__float_as_uint(lo) >> 16);
        }
    }
    __syncthreads();

    // ---- phase 1: MFMA projections ----
    const int lane = tid & 63;
    const int w8   = tid >> 6;          // wave 0..7
    const int wm   = w8 >> 1;           // row subtile 0..3
    const int wc   = w8 & 1;            // col subtile 0..1
    const int lr   = lane & 15;         // A-row / B-col within tile
    const int lg   = lane >> 4;         // k-group 0..3
    const int cloc  = wc * 16 + lr;     // 0..31 col within slab
    const int cglob = cbase + cloc;
    const int rowA  = mg * 64 + wm * 16 + lr;   // row this lane's A-frag feeds

    f32x4 qa = {0.f, 0.f, 0.f, 0.f};
    f32x4 ka = {0.f, 0.f, 0.f, 0.f};
    f32x4 va = {0.f, 0.f, 0.f, 0.f};

    const float* xrow = x + (size_t)rowA * DD;

#pragma unroll
    for (int s = 0; s < 4; ++s) {
        const int koff = s * 32 + lg * 8;
        // A frag: x[rowA][koff..koff+7] fp32 -> bf16 hi/lo
        const float4 x0 = *reinterpret_cast<const float4*>(xrow + koff);
        const float4 x1 = *reinterpret_cast<const float4*>(xrow + koff + 4);
        const float xv[8] = {x0.x, x0.y, x0.z, x0.w, x1.x, x1.y, x1.z, x1.w};
        float xl[8];
#pragma unroll
        for (int j = 0; j < 8; ++j)
            xl[j] = xv[j] - __uint_as_float(__float_as_uint(xv[j]) & 0xFFFF0000u);
        AB ah, al;
#pragma unroll
        for (int j = 0; j < 4; ++j) {
            ah.u[j] = pack_bf16(xv[2 * j], xv[2 * j + 1]);
            al.u[j] = pack_bf16(xl[2 * j], xl[2 * j + 1]);
        }
        // B frags from LDS (per-lane distinct addrs, uniform bank spread)
        AB qh, ql, kh, kl, vh, vl;
        qh.s = *reinterpret_cast<const short8*>(&wt[0][0][cloc][koff]);
        ql.s = *reinterpret_cast<const short8*>(&wt[0][1][cloc][koff]);
        kh.s = *reinterpret_cast<const short8*>(&wt[1][0][cloc][koff]);
        kl.s = *reinterpret_cast<const short8*>(&wt[1][1][cloc][koff]);
        vh.s = *reinterpret_cast<const short8*>(&wt[2][0][cloc][koff]);
        vl.s = *reinterpret_cast<const short8*>(&wt[2][1][cloc][koff]);

        qa = __builtin_amdgcn_mfma_f32_16x16x32_bf16(ah.s, qh.s, qa, 0, 0, 0);
        qa = __builtin_amdgcn_mfma_f32_16x16x32_bf16(al.s, qh.s, qa, 0, 0, 0);
        qa = __builtin_amdgcn_mfma_f32_16x16x32_bf16(ah.s, ql.s, qa, 0, 0, 0);

        ka = __builtin_amdgcn_mfma_f32_16x16x32_bf16(ah.s, kh.s, ka, 0, 0, 0);
        ka = __builtin_amdgcn_mfma_f32_16x16x32_bf16(al.s, kh.s, ka, 0, 0, 0);
        ka = __builtin_amdgcn_mfma_f32_16x16x32_bf16(ah.s, kl.s, ka, 0, 0, 0);

        va = __builtin_amdgcn_mfma_f32_16x16x32_bf16(ah.s, vh.s, va, 0, 0, 0);
        va = __builtin_amdgcn_mfma_f32_16x16x32_bf16(al.s, vh.s, va, 0, 0, 0);
        va = __builtin_amdgcn_mfma_f32_16x16x32_bf16(ah.s, vl.s, va, 0, 0, 0);
    }

    // per-lane biases (col = cglob); bq/bk/bv are tiny, L2-resident
    const float bkc = bk[cglob], bvc = bv[cglob], bqc = bq[cglob];

    // k*v summed over this wave's 16 rows (4 regs, then across the 4 row-groups)
    float ps = 0.f;
#pragma unroll
    for (int i = 0; i < 4; ++i)
        ps += (ka[i] + bkc) * (va[i] + bvc);
    ps += __shfl_xor(ps, 16);
    ps += __shfl_xor(ps, 32);
    if (lane < 16) red[w8][cloc] = ps;
    __syncthreads();

    // block partial over the 4 row-subtile waves -> ws[b][cp][mg&15][32]
    if (tid < 32) {
        const int wcq = tid >> 4;
        const float s = red[wcq][tid] + red[wcq + 2][tid] +
                        red[wcq + 4][tid] + red[wcq + 6][tid];
        ws[(((b * 4 + cp) * 16) + (mg & 15)) * 32 + tid] = s;
    }

    grid.sync();

    // ---- phase 2: kv reduce (fixed order) + scale q from registers ----
    float kvc = 0.f;
    {
        const float* pp = ws + (size_t)((b * 4 + cp) * 16) * 32 + cloc;
#pragma unroll
        for (int j = 0; j < 16; ++j) kvc += pp[j * 32];
    }
    const size_t rbase = (size_t)(mg * 64 + wm * 16 + lg * 4) * DD + cglob;
#pragma unroll
    for (int i = 0; i < 4; ++i)
        out[rbase + (size_t)i * DD] = (qa[i] + bqc) * kvc;
}

extern "C" void kernel_launch(void* const* d_in, const int* in_sizes, int n_in,
                              void* d_out, int out_size, void* d_ws, size_t ws_size,
                              hipStream_t stream) {
    const float* x  = (const float*)d_in[0];
    const float* Wq = (const float*)d_in[1];
    const float* bq = (const float*)d_in[2];
    const float* Wk = (const float*)d_in[3];
    const float* bk = (const float*)d_in[4];
    const float* Wv = (const float*)d_in[5];
    const float* bv = (const float*)d_in[6];
    float* out      = (float*)d_out;
    float* ws       = (float*)d_ws;    // partials: 4*4*16*32 floats = 32 KB

    void* args[] = {(void*)&x, (void*)&Wq, (void*)&bq, (void*)&Wk, (void*)&bk,
                    (void*)&Wv, (void*)&bv, (void*)&out, (void*)&ws};
    hipLaunchCooperativeKernel((const void*)fused, dim3(BB * 16 * 4), dim3(512),
                               args, 0, stream);
}

// Round 3
// 32.330 us; speedup vs baseline: 1.3787x; 1.3787x over previous
//
#include <hip/hip_runtime.h>

// out[b,n,d] = (x@Wq+bq)[b,n,d] * kv[b,d],  kv[b,d] = sum_m ((x@Wk+bk)*(x@Wv+bv))[b,m,d]
// B=4, N=1024, D=128, fp32.
//
// R3: baseline macro-structure (proj -> partials, then scale), rebuilt micro:
//  - grid 1024 = 8cg x (4b x 32 rowtiles of 32 rows): 4 blocks/CU -> 4 waves/SIMD
//    (baseline was 2), AND per-lane k-chain halved (lane = row + 32*khalf).
//  - W streamed via VMEM float4 loads (in-order vmcnt -> compiler pipelines the
//    fully-unrolled loop); x from LDS on lgkmcnt only. No SMEM/LDS counter mixing.
//  - x tile stored UNPADDED (32x128 floats = 16 KB) with XOR swizzle
//    chunk' = chunk ^ (row&7): ds_read_b128 lands 8 lanes per 4-bank slot
//    = the b128 bank floor (conflict-free); staging writes 2-way (free).
//  - cg in HIGH bits of blockIdx: the 8 blocks sharing one x-tile differ by
//    128 in blockIdx -> same XCD under round-robin -> x fetched once per tile.

#define BB 4
#define NN 1024
#define DD 128
#define RT 32              // rows per block tile
#define NT 32              // rowtiles per batch
#define NBT (BB * NT)      // 128 (b,t) tiles

static __device__ __forceinline__ void fma4(float4& a, float s, float4 m) {
    a.x = fmaf(s, m.x, a.x);
    a.y = fmaf(s, m.y, a.y);
    a.z = fmaf(s, m.z, a.z);
    a.w = fmaf(s, m.w, a.w);
}

__global__ __launch_bounds__(256, 4) void proj_kernel(
    const float* __restrict__ x,
    const float* __restrict__ Wq, const float* __restrict__ bq,
    const float* __restrict__ Wk, const float* __restrict__ bk,
    const float* __restrict__ Wv, const float* __restrict__ bv,
    float* __restrict__ qout, float* __restrict__ partials)
{
    __shared__ float xs[RT * DD];               // 16 KB, swizzled, no pad
    const int bid = blockIdx.x;                 // 1024 = cg(8) x bt(128)
    const int bt  = bid & (NBT - 1);
    const int cg  = bid >> 7;
    const int b   = bt >> 5;
    const int t   = bt & (NT - 1);
    const int tid = threadIdx.x;

    // ---- stage x tile [32 rows][32 float4-chunks], chunk ^= (row&7) ----
    {
        const float4* src = reinterpret_cast<const float4*>(
            x + ((size_t)b * NN + (size_t)t * RT) * DD);
#pragma unroll
        for (int j = 0; j < 4; ++j) {
            const int idx = tid + j * 256;      // 0..1023 float4s, coalesced
            const float4 v = src[idx];
            const int r = idx >> 5, c = idx & 31;
            *reinterpret_cast<float4*>(&xs[r * DD + ((c ^ (r & 7)) << 2)]) = v;
        }
    }
    __syncthreads();

    const int lane = tid & 63;
    const int w    = tid >> 6;
    const int row  = lane & 31;                 // row within tile
    const int kh   = lane >> 5;                 // k-half: 0 -> k<64, 1 -> k>=64
    const int cw   = (cg << 2) + w;             // float4-column 0..31

    const float4* Wq4 = reinterpret_cast<const float4*>(Wq) + cw;
    const float4* Wk4 = reinterpret_cast<const float4*>(Wk) + cw;
    const float4* Wv4 = reinterpret_cast<const float4*>(Wv) + cw;

    float4 qa = {0.f, 0.f, 0.f, 0.f};
    float4 ka = {0.f, 0.f, 0.f, 0.f};
    float4 va = {0.f, 0.f, 0.f, 0.f};

    const float* xrow = &xs[row * DD];
    const int swz = row & 7;

#pragma unroll
    for (int g = 0; g < 16; ++g) {
        const int chunk = (kh << 4) + g;        // this lane's float4-chunk of k
        const float4 xv = *reinterpret_cast<const float4*>(
            &xrow[((chunk ^ swz) << 2)]);
        const int k0 = chunk << 2;
        fma4(qa, xv.x, Wq4[(k0 + 0) * 32]);
        fma4(ka, xv.x, Wk4[(k0 + 0) * 32]);
        fma4(va, xv.x, Wv4[(k0 + 0) * 32]);
        fma4(qa, xv.y, Wq4[(k0 + 1) * 32]);
        fma4(ka, xv.y, Wk4[(k0 + 1) * 32]);
        fma4(va, xv.y, Wv4[(k0 + 1) * 32]);
        fma4(qa, xv.z, Wq4[(k0 + 2) * 32]);
        fma4(ka, xv.z, Wk4[(k0 + 2) * 32]);
        fma4(va, xv.z, Wv4[(k0 + 2) * 32]);
        fma4(qa, xv.w, Wq4[(k0 + 3) * 32]);
        fma4(ka, xv.w, Wk4[(k0 + 3) * 32]);
        fma4(va, xv.w, Wv4[(k0 + 3) * 32]);
    }

    // combine the two k-halves (partner lane = same row, other kh)
    qa.x += __shfl_xor(qa.x, 32); qa.y += __shfl_xor(qa.y, 32);
    qa.z += __shfl_xor(qa.z, 32); qa.w += __shfl_xor(qa.w, 32);
    ka.x += __shfl_xor(ka.x, 32); ka.y += __shfl_xor(ka.y, 32);
    ka.z += __shfl_xor(ka.z, 32); ka.w += __shfl_xor(ka.w, 32);
    va.x += __shfl_xor(va.x, 32); va.y += __shfl_xor(va.y, 32);
    va.z += __shfl_xor(va.z, 32); va.w += __shfl_xor(va.w, 32);

    const float4 bq4 = reinterpret_cast<const float4*>(bq)[cw];
    const float4 bk4 = reinterpret_cast<const float4*>(bk)[cw];
    const float4 bv4 = reinterpret_cast<const float4*>(bv)[cw];

    // q -> out (kh==0 lanes; 32 rows x one float4 col)
    if (kh == 0) {
        float4 qo;
        qo.x = qa.x + bq4.x; qo.y = qa.y + bq4.y;
        qo.z = qa.z + bq4.z; qo.w = qa.w + bq4.w;
        reinterpret_cast<float4*>(qout)[
            ((size_t)b * NN + (size_t)t * RT + row) * 32 + cw] = qo;
    }

    // kv partial: per-row (k+bk)*(v+bv), butterfly over the 32 rows
    float4 p;
    p.x = (ka.x + bk4.x) * (va.x + bv4.x);
    p.y = (ka.y + bk4.y) * (va.y + bv4.y);
    p.z = (ka.z + bk4.z) * (va.z + bv4.z);
    p.w = (ka.w + bk4.w) * (va.w + bv4.w);
#pragma unroll
    for (int off = 1; off < 32; off <<= 1) {
        p.x += __shfl_xor(p.x, off);
        p.y += __shfl_xor(p.y, off);
        p.z += __shfl_xor(p.z, off);
        p.w += __shfl_xor(p.w, off);
    }
    if (lane == 0)
        reinterpret_cast<float4*>(partials)[(size_t)bt * 32 + cw] = p;
}

__global__ __launch_bounds__(256) void scale_kernel(
    const float* __restrict__ partials, float* __restrict__ out)
{
    __shared__ float kvs[DD];
    const int blk = blockIdx.x;          // 256 = b(4) x tt(64 tiles of 16 rows)
    const int b = blk >> 6, tt = blk & 63;
    const int tid = threadIdx.x;

    if (tid < DD) {
        float s = 0.f;
        const float* pp = partials + (size_t)b * NT * DD + tid;
#pragma unroll
        for (int j = 0; j < NT; ++j) s += pp[(size_t)j * DD];  // fixed order
        kvs[tid] = s;
    }
    __syncthreads();

    float4* o4 = reinterpret_cast<float4*>(out + ((size_t)b * NN + (size_t)tt * 16) * DD);
    const float4* kv4 = reinterpret_cast<const float4*>(kvs);
#pragma unroll
    for (int r = 0; r < 2; ++r) {
        const int idx = tid + r * 256;    // 512 float4s = 16 rows x 32
        float4 v = o4[idx];
        const float4 kk = kv4[idx & 31];
        v.x *= kk.x; v.y *= kk.y; v.z *= kk.z; v.w *= kk.w;
        o4[idx] = v;
    }
}

extern "C" void kernel_launch(void* const* d_in, const int* in_sizes, int n_in,
                              void* d_out, int out_size, void* d_ws, size_t ws_size,
                              hipStream_t stream) {
    const float* x  = (const float*)d_in[0];
    const float* Wq = (const float*)d_in[1];
    const float* bq = (const float*)d_in[2];
    const float* Wk = (const float*)d_in[3];
    const float* bk = (const float*)d_in[4];
    const float* Wv = (const float*)d_in[5];
    const float* bv = (const float*)d_in[6];
    float* out      = (float*)d_out;
    float* partials = (float*)d_ws;   // 4*32*128 floats = 64 KB

    proj_kernel<<<dim3(8 * NBT), dim3(256), 0, stream>>>(
        x, Wq, bq, Wk, bk, Wv, bv, out, partials);
    scale_kernel<<<dim3(BB * (NN / 16)), dim3(256), 0, stream>>>(partials, out);
}

// Round 4
// 19.251 us; speedup vs baseline: 2.3154x; 1.6794x over previous
//
#include <hip/hip_runtime.h>

// out[b,n,d] = (x@Wq+bq)[b,n,d] * kv[b,d],  kv[b,d] = sum_m ((x@Wk+bk)*(x@Wv+bv))[b,m,d]
// B=4, N=1024, D=128, fp32.
//
// R4: inner loop runs ENTIRELY from LDS (x per-lane + W broadcast), killing the
// serialized long-latency W stream that capped R0 (SMEM, 23.7us) and R1/R3
// (VMEM, ~32us):
//  - block = 512 thr (8 waves) = 32 rows x 32 cols; W slab (3 x 128k x 32c,
//    48 KB) staged once per block into LDS; x tile (32x128, 16 KB) XOR-swizzled.
//  - inner loop per 4-k group: 1 per-lane ds_read_b128 (x, bank floor) +
//    12 wave-uniform ds_read_b128 (W, broadcast, conflict-free) + 48 v_fma
//    -> VALU-bound; all loads on in-order lgkmcnt, compiler emits partial waits.
//  - 512 blocks = 2/CU (64 KB LDS each), 4 waves/SIMD, VGPR cap 128.
//  - cg in HIGH bits: the 4 blocks sharing an x tile differ by 128 in blockIdx
//    -> same XCD -> x fetched once per tile. W slabs are L2-resident (192 KB).

#define BB 4
#define NN 1024
#define DD 128
#define RT 32              // rows per block tile
#define NT 32              // rowtiles per batch
#define NBT (BB * NT)      // 128 (b,t) tiles

static __device__ __forceinline__ void fma4(float4& a, float s, float4 m) {
    a.x = fmaf(s, m.x, a.x);
    a.y = fmaf(s, m.y, a.y);
    a.z = fmaf(s, m.z, a.z);
    a.w = fmaf(s, m.w, a.w);
}

__global__ __launch_bounds__(512, 4) void proj_kernel(
    const float* __restrict__ x,
    const float* __restrict__ Wq, const float* __restrict__ bq,
    const float* __restrict__ Wk, const float* __restrict__ bk,
    const float* __restrict__ Wv, const float* __restrict__ bv,
    float* __restrict__ qout, float* __restrict__ partials)
{
    __shared__ float xs[RT * DD];        // 16 KB, XOR-swizzled
    __shared__ float wt[3][DD][32];      // 48 KB: [mat][k][col-in-slab]
    const int bid = blockIdx.x;          // 512 = cg(4) x bt(128)
    const int bt  = bid & (NBT - 1);
    const int cg  = bid >> 7;            // 0..3 -> cols cg*32 .. cg*32+31
    const int b   = bt >> 5;
    const int t   = bt & (NT - 1);
    const int tid = threadIdx.x;

    // ---- stage W slab (3 x 1024 float4s, 2 per thread per mat) ----
    {
        const float4* s0 = reinterpret_cast<const float4*>(Wq) + (cg << 3);
        const float4* s1 = reinterpret_cast<const float4*>(Wk) + (cg << 3);
        const float4* s2 = reinterpret_cast<const float4*>(Wv) + (cg << 3);
#pragma unroll
        for (int j = 0; j < 2; ++j) {
            const int e  = tid + j * 512;        // 0..1023 float4s per mat
            const int k  = e >> 3, c4 = e & 7;   // k row, float4-col in slab
            const float4 a0 = s0[k * 32 + c4];   // row stride = 32 float4s
            const float4 a1 = s1[k * 32 + c4];
            const float4 a2 = s2[k * 32 + c4];
            *reinterpret_cast<float4*>(&wt[0][k][c4 << 2]) = a0;
            *reinterpret_cast<float4*>(&wt[1][k][c4 << 2]) = a1;
            *reinterpret_cast<float4*>(&wt[2][k][c4 << 2]) = a2;
        }
    }
    // ---- stage x tile [32 rows][32 chunks], chunk ^= (row&7) ----
    {
        const float4* src = reinterpret_cast<const float4*>(
            x + ((size_t)b * NN + (size_t)t * RT) * DD);
#pragma unroll
        for (int j = 0; j < 2; ++j) {
            const int idx = tid + j * 512;       // 0..1023 float4s, coalesced
            const float4 v = src[idx];
            const int r = idx >> 5, c = idx & 31;
            *reinterpret_cast<float4*>(&xs[r * DD + ((c ^ (r & 7)) << 2)]) = v;
        }
    }
    __syncthreads();

    const int lane = tid & 63;
    const int w8   = tid >> 6;           // wave 0..7
    const int row  = lane & 31;          // row within tile
    const int kh   = lane >> 5;          // k-half
    const int cw   = (cg << 3) + w8;     // float4-column 0..31 (uniform)

    float4 qa = {0.f, 0.f, 0.f, 0.f};
    float4 ka = {0.f, 0.f, 0.f, 0.f};
    float4 va = {0.f, 0.f, 0.f, 0.f};

    const float* xrow = &xs[row * DD];
    const int swz = row & 7;
    const int wc4 = w8 << 2;             // wave's float4-col offset in slab

#define WF4(m, k) (*reinterpret_cast<const float4*>(&wt[m][k][wc4]))

#pragma unroll
    for (int g = 0; g < 16; ++g) {
        const int chunk = (kh << 4) + g;
        const float4 xv = *reinterpret_cast<const float4*>(
            &xrow[(chunk ^ swz) << 2]);
        const int k0 = chunk << 2;
        fma4(qa, xv.x, WF4(0, k0 + 0));
        fma4(ka, xv.x, WF4(1, k0 + 0));
        fma4(va, xv.x, WF4(2, k0 + 0));
        fma4(qa, xv.y, WF4(0, k0 + 1));
        fma4(ka, xv.y, WF4(1, k0 + 1));
        fma4(va, xv.y, WF4(2, k0 + 1));
        fma4(qa, xv.z, WF4(0, k0 + 2));
        fma4(ka, xv.z, WF4(1, k0 + 2));
        fma4(va, xv.z, WF4(2, k0 + 2));
        fma4(qa, xv.w, WF4(0, k0 + 3));
        fma4(ka, xv.w, WF4(1, k0 + 3));
        fma4(va, xv.w, WF4(2, k0 + 3));
    }
#undef WF4

    // combine the two k-halves (partner lane = same row, other kh)
    qa.x += __shfl_xor(qa.x, 32); qa.y += __shfl_xor(qa.y, 32);
    qa.z += __shfl_xor(qa.z, 32); qa.w += __shfl_xor(qa.w, 32);
    ka.x += __shfl_xor(ka.x, 32); ka.y += __shfl_xor(ka.y, 32);
    ka.z += __shfl_xor(ka.z, 32); ka.w += __shfl_xor(ka.w, 32);
    va.x += __shfl_xor(va.x, 32); va.y += __shfl_xor(va.y, 32);
    va.z += __shfl_xor(va.z, 32); va.w += __shfl_xor(va.w, 32);

    const float4 bq4 = reinterpret_cast<const float4*>(bq)[cw];
    const float4 bk4 = reinterpret_cast<const float4*>(bk)[cw];
    const float4 bv4 = reinterpret_cast<const float4*>(bv)[cw];

    // q -> out (kh==0 lanes: 32 rows x one float4 col; block writes 128B/row)
    if (kh == 0) {
        float4 qo;
        qo.x = qa.x + bq4.x; qo.y = qa.y + bq4.y;
        qo.z = qa.z + bq4.z; qo.w = qa.w + bq4.w;
        reinterpret_cast<float4*>(qout)[
            ((size_t)b * NN + (size_t)t * RT + row) * 32 + cw] = qo;
    }

    // kv partial: per-row (k+bk)*(v+bv), butterfly over 32 rows in each half
    float4 p;
    p.x = (ka.x + bk4.x) * (va.x + bv4.x);
    p.y = (ka.y + bk4.y) * (va.y + bv4.y);
    p.z = (ka.z + bk4.z) * (va.z + bv4.z);
    p.w = (ka.w + bk4.w) * (va.w + bv4.w);
#pragma unroll
    for (int off = 1; off < 32; off <<= 1) {
        p.x += __shfl_xor(p.x, off);
        p.y += __shfl_xor(p.y, off);
        p.z += __shfl_xor(p.z, off);
        p.w += __shfl_xor(p.w, off);
    }
    if (lane == 0)
        reinterpret_cast<float4*>(partials)[(size_t)bt * 32 + cw] = p;
}

__global__ __launch_bounds__(256) void scale_kernel(
    const float* __restrict__ partials, float* __restrict__ out)
{
    __shared__ float kvs[DD];
    const int blk = blockIdx.x;          // 256 = b(4) x tt(64 tiles of 16 rows)
    const int b = blk >> 6, tt = blk & 63;
    const int tid = threadIdx.x;

    if (tid < DD) {
        float s = 0.f;
        const float* pp = partials + (size_t)b * NT * DD + tid;
#pragma unroll
        for (int j = 0; j < NT; ++j) s += pp[(size_t)j * DD];  // fixed order
        kvs[tid] = s;
    }
    __syncthreads();

    float4* o4 = reinterpret_cast<float4*>(out + ((size_t)b * NN + (size_t)tt * 16) * DD);
    const float4* kv4 = reinterpret_cast<const float4*>(kvs);
#pragma unroll
    for (int r = 0; r < 2; ++r) {
        const int idx = tid + r * 256;    // 512 float4s = 16 rows x 32
        float4 v = o4[idx];
        const float4 kk = kv4[idx & 31];
        v.x *= kk.x; v.y *= kk.y; v.z *= kk.z; v.w *= kk.w;
        o4[idx] = v;
    }
}

extern "C" void kernel_launch(void* const* d_in, const int* in_sizes, int n_in,
                              void* d_out, int out_size, void* d_ws, size_t ws_size,
                              hipStream_t stream) {
    const float* x  = (const float*)d_in[0];
    const float* Wq = (const float*)d_in[1];
    const float* bq = (const float*)d_in[2];
    const float* Wk = (const float*)d_in[3];
    const float* bk = (const float*)d_in[4];
    const float* Wv = (const float*)d_in[5];
    const float* bv = (const float*)d_in[6];
    float* out      = (float*)d_out;
    float* partials = (float*)d_ws;   // 4*32*128 floats = 64 KB

    proj_kernel<<<dim3(4 * NBT), dim3(512), 0, stream>>>(
        x, Wq, bq, Wk, bk, Wv, bv, out, partials);
    scale_kernel<<<dim3(BB * (NN / 16)), dim3(256), 0, stream>>>(partials, out);
}